// Round 7
// baseline (33.745 us; speedup 1.0000x reference)
//
#include <hip/hip_runtime.h>
#include <math.h>

// out[b,o] = min_i(W[o,i]+X[b,i]) + max_i(W[o,i]+X[b,i])
// B=1024, OUT=1024, IN=512, fp32.
//
// R7: TLP fix. Tile 64x32, grid 512 blocks (2/CU) but 512-thread / 8-wave
// blocks -> 16 waves/CU = 4 waves/SIMD feeding the per-CU LDS pipe (R6 was
// 2/SIMD, ~60% of LDS-pipe floor). Wave k-slice = 64. Single LOADQ register
// set (live-set ~118 VGPR, must stay <=128 for 2-block residency).
// Wave-private double-buffered LDS (6KB/wave), zero main-loop barriers,
// asm v_min3/v_max3, 3-round macro merge tree.

typedef float f4 __attribute__((ext_vector_type(4)));

constexpr int B_DIM  = 1024;
constexpr int O_DIM  = 1024;
constexpr int IN_DIM = 512;

constexpr int TM     = 64;           // batch-tile
constexpr int TN     = 32;           // out-tile
constexpr int KW     = 64;           // k per wave (512 / 8 waves)
constexpr int BK     = 8;            // k per stage
constexpr int NSTAGE = KW / BK;      // 8

__global__ __launch_bounds__(512, 4) void tropical_gemm(
    const float* __restrict__ X, const float* __restrict__ W,
    float* __restrict__ out) {
    __shared__ float lds[16384];   // 64 KB: loop 8x1536 (48KB), merge 4x4096 overlay

    const int tid  = threadIdx.x;
    const int w    = tid >> 6;     // wave 0..7
    const int lane = tid & 63;
    const int im   = lane >> 3;    // micro-row block 0..7 (8 X rows)
    const int in_  = lane & 7;     // micro-col block 0..7 (4 W cols)
    const int b0   = blockIdx.y * TM;
    const int o0   = blockIdx.x * TN;
    const int xoff = im * 8;
    const int woff = in_ * 4;
    const int wrow = lane >> 1;            // W staging: 2 lanes per row
    const int wk4  = (lane & 1) * 4;       // which k-half of the row's 8

    const float* Xp = X + (size_t)(b0 + lane) * IN_DIM + w * KW;
    const float* Wp = W + (size_t)(o0 + wrow) * IN_DIM + w * KW + wk4;

    float* wbase = &lds[w * 1536];  // wave-private: [buf2][X 8x64 | W 8x32]

    float mn[8][4], mx[8][4];
#pragma unroll
    for (int i = 0; i < 8; ++i)
#pragma unroll
        for (int j = 0; j < 4; ++j) { mn[i][j] = INFINITY; mx[i][j] = -INFINITY; }

    // stage one 8k chunk: X k-major [k][64], W k-major [k][32]
#define STAGE(bufsel)                                                         \
    do {                                                                      \
        float* d_ = wbase + (bufsel) * 768;                                   \
        _Pragma("unroll")                                                     \
        for (int j_ = 0; j_ < 4; ++j_) {                                      \
            d_[j_ * 64 + lane]       = xa[j_];                                \
            d_[(4 + j_) * 64 + lane] = xb[j_];                                \
            d_[512 + (wk4 + j_) * 32 + wrow] = wv[j_];                        \
        }                                                                     \
    } while (0)

    // ---- prologue ----
    f4 xa = *(const f4*)(Xp);
    f4 xb = *(const f4*)(Xp + 4);
    f4 wv = *(const f4*)(Wp);
    STAGE(0);

#pragma unroll 1
    for (int s = 0; s < NSTAGE; ++s) {
        if (s + 1 < NSTAGE) {  // prefetch next chunk's globals
            xa = *(const f4*)(Xp + (s + 1) * BK);
            xb = *(const f4*)(Xp + (s + 1) * BK + 4);
            wv = *(const f4*)(Wp + (s + 1) * BK);
        }

        const float* sXf = wbase + (s & 1) * 768;
        const float* sWf = sXf + 512;

#pragma unroll
        for (int kp = 0; kp < 4; ++kp) {
            f4 x0  = *(const f4*)(sXf + (2 * kp) * 64 + xoff);
            f4 x0b = *(const f4*)(sXf + (2 * kp) * 64 + xoff + 4);
            f4 x1  = *(const f4*)(sXf + (2 * kp + 1) * 64 + xoff);
            f4 x1b = *(const f4*)(sXf + (2 * kp + 1) * 64 + xoff + 4);
            f4 w0  = *(const f4*)(sWf + (2 * kp) * 32 + woff);
            f4 w1  = *(const f4*)(sWf + (2 * kp + 1) * 32 + woff);
#pragma unroll
            for (int a = 0; a < 8; ++a) {
                const float xv0 = (a < 4) ? x0[a] : x0b[a - 4];
                const float xv1 = (a < 4) ? x1[a] : x1b[a - 4];
#pragma unroll
                for (int b = 0; b < 4; ++b) {
                    float s0 = xv0 + w0[b];
                    float s1 = xv1 + w1[b];
                    asm("v_min3_f32 %0, %1, %2, %0"
                        : "+v"(mn[a][b]) : "v"(s0), "v"(s1));
                    asm("v_max3_f32 %0, %1, %2, %0"
                        : "+v"(mx[a][b]) : "v"(s0), "v"(s1));
                }
            }
        }

        if (s + 1 < NSTAGE) STAGE((s + 1) & 1);
    }
#undef STAGE

    // ---- merge 8 wave partials: 3-round LDS tree ----
    // per-wave state = 4096 floats: q=r -> mn[r][0..3], q=8+r -> mx[r][0..3]
#define DUMP_STATE(slotbase)                                                  \
    do {                                                                      \
        float* p_ = (slotbase) + lane * 4;                                    \
        _Pragma("unroll")                                                     \
        for (int r_ = 0; r_ < 8; ++r_) {                                      \
            *(float4*)(p_ + r_ * 256) =                                       \
                make_float4(mn[r_][0], mn[r_][1], mn[r_][2], mn[r_][3]);      \
            *(float4*)(p_ + (8 + r_) * 256) =                                 \
                make_float4(mx[r_][0], mx[r_][1], mx[r_][2], mx[r_][3]);      \
        }                                                                     \
    } while (0)

#define MERGE_STATE(slotbase)                                                 \
    do {                                                                      \
        const float* p_ = (slotbase) + lane * 4;                              \
        _Pragma("unroll")                                                     \
        for (int r_ = 0; r_ < 8; ++r_) {                                      \
            float4 vn_ = *(const float4*)(p_ + r_ * 256);                     \
            float4 vx_ = *(const float4*)(p_ + (8 + r_) * 256);               \
            mn[r_][0] = fminf(mn[r_][0], vn_.x);                              \
            mn[r_][1] = fminf(mn[r_][1], vn_.y);                              \
            mn[r_][2] = fminf(mn[r_][2], vn_.z);                              \
            mn[r_][3] = fminf(mn[r_][3], vn_.w);                              \
            mx[r_][0] = fmaxf(mx[r_][0], vx_.x);                              \
            mx[r_][1] = fmaxf(mx[r_][1], vx_.y);                              \
            mx[r_][2] = fmaxf(mx[r_][2], vx_.z);                              \
            mx[r_][3] = fmaxf(mx[r_][3], vx_.w);                              \
        }                                                                     \
    } while (0)

    float* const slot0 = lds;            // 4 slots x 4096 floats = 64 KB
    float* const slot1 = lds + 4096;
    float* const slot2 = lds + 8192;
    float* const slot3 = lds + 12288;

    __syncthreads();                     // main-loop LDS use complete
    // Round 1: 8 -> 4
    if (w == 4) DUMP_STATE(slot0);
    if (w == 5) DUMP_STATE(slot1);
    if (w == 6) DUMP_STATE(slot2);
    if (w == 7) DUMP_STATE(slot3);
    __syncthreads();
    if (w == 0) MERGE_STATE(slot0);
    if (w == 1) MERGE_STATE(slot1);
    if (w == 2) MERGE_STATE(slot2);
    if (w == 3) MERGE_STATE(slot3);
    __syncthreads();
    // Round 2: 4 -> 2
    if (w == 2) DUMP_STATE(slot0);
    if (w == 3) DUMP_STATE(slot1);
    __syncthreads();
    if (w == 0) MERGE_STATE(slot0);
    if (w == 1) MERGE_STATE(slot1);
    __syncthreads();
    // Round 3: 2 -> 1
    if (w == 1) DUMP_STATE(slot0);
    __syncthreads();
    if (w == 0) {
        MERGE_STATE(slot0);
        float* op = out + (size_t)(b0 + im * 8) * O_DIM + o0 + in_ * 4;
#pragma unroll
        for (int r = 0; r < 8; ++r)
            *(float4*)(op + (size_t)r * O_DIM) =
                make_float4(mn[r][0] + mx[r][0], mn[r][1] + mx[r][1],
                            mn[r][2] + mx[r][2], mn[r][3] + mx[r][3]);
    }
#undef DUMP_STATE
#undef MERGE_STATE
}

extern "C" void kernel_launch(void* const* d_in, const int* in_sizes, int n_in,
                              void* d_out, int out_size, void* d_ws, size_t ws_size,
                              hipStream_t stream) {
    (void)in_sizes; (void)n_in; (void)d_ws; (void)ws_size; (void)out_size;
    const float* X = (const float*)d_in[0];
    const float* W = (const float*)d_in[1];
    float* out     = (float*)d_out;

    dim3 grid(O_DIM / TN, B_DIM / TM);  // (32, 16) = 512 blocks = 2/CU
    tropical_gemm<<<grid, dim3(512), 0, stream>>>(X, W, out);
}